// Round 3
// baseline (155.627 us; speedup 1.0000x reference)
//
#include <hip/hip_runtime.h>
#include <hip/hip_bf16.h>

#define NL    64
#define DIN   512
#define DOUT  512
#define BATCH 1024

#define BM 128
#define BN 128
#define BK 64
#define NK (DIN / BK)   // 8

typedef short short8 __attribute__((ext_vector_type(8)));
typedef float f32x4  __attribute__((ext_vector_type(4)));

__device__ __forceinline__ unsigned int pk2(float a, float b) {
    // lowers to v_cvt_pk_bf16_f32 (RNE); memcpy instead of bit_cast
    // (__hip_bfloat162 is not trivially copyable)
    __hip_bfloat162 h = __float22bfloat162_rn(make_float2(a, b));
    unsigned int r;
    __builtin_memcpy(&r, &h, 4);
    return r;
}

__global__ __launch_bounds__(256) void nlinear_kernel(
        const float* __restrict__ x, const float* __restrict__ w,
        const float* __restrict__ bias, float* __restrict__ out) {
    // bf16 tiles, linear 128B rows, XOR-swizzled 16B slots: slot ^= (row>>1)&7
    __shared__ unsigned short As[BM * BK];   // 16 KB  [m][k]
    __shared__ unsigned short Bs[BN * BK];   // 16 KB  [n][k] (transposed at stage)

    const int tid = threadIdx.x;

    // XCD swizzle: 2048 blocks = 8 XCDs x 256; 32 consecutive tiles/layer stay on one XCD
    const int bid   = blockIdx.x;
    const int nb    = (bid & 7) * 256 + (bid >> 3);
    const int layer = nb >> 5;
    const int tile  = nb & 31;
    const int bm0   = (tile >> 2) * BM;
    const int bn0   = (tile & 3) * BN;

    const int wid  = tid >> 6;
    const int lane = tid & 63;
    const int wr   = wid >> 1, wc = wid & 1;   // 2x2 waves, 64x64 each
    const int lrow = lane & 15;
    const int lkb  = lane >> 4;
    const int lswz = ((lrow >> 1) & 7) << 3;   // frag-read swizzle, ushort units

    // A staging: 2 threads/row, 32 consecutive k each
    const int arow  = tid >> 1;
    const int ahalf = tid & 1;
    const int aswz  = ((arow >> 1) & 7) << 3;
    // B staging: thread owns 4 n-cols x 8 k-rows (4x8 transpose block)
    const int gn = tid & 31;
    const int gk = tid >> 5;

    const float* xb = x + (size_t)bm0 * (NL * DIN) + (size_t)layer * DIN;
    const float* wb = w + (size_t)layer * DIN * DOUT + bn0;
    const float* aptr0 = xb + (size_t)arow * (NL * DIN) + ahalf * 32;
    const float* bptr0 = wb + (size_t)(gk * 8) * DOUT + gn * 4;

    f32x4 acc[4][4];
#pragma unroll
    for (int i = 0; i < 4; ++i)
#pragma unroll
        for (int j = 0; j < 4; ++j) acc[i][j] = (f32x4){0.f, 0.f, 0.f, 0.f};

    f32x4 av[8], bv[8];
    // prologue: tile 0 into regs
#pragma unroll
    for (int i = 0; i < 8; ++i)
        av[i] = *reinterpret_cast<const f32x4*>(aptr0 + i * 4);
#pragma unroll
    for (int i = 0; i < 8; ++i)
        bv[i] = *reinterpret_cast<const f32x4*>(bptr0 + (size_t)i * DOUT);

    for (int ks = 0; ks < NK; ++ks) {
        __syncthreads();   // LDS free (previous tile's reads done)

        // ---- convert & write A: 4x ds_write_b128, slot (ahalf*4+i)^swz ----
        {
            unsigned short* rowp = &As[arow * BK];
#pragma unroll
            for (int i = 0; i < 4; ++i) {
                uint4 wv;
                wv.x = pk2(av[2*i][0],   av[2*i][1]);
                wv.y = pk2(av[2*i][2],   av[2*i][3]);
                wv.z = pk2(av[2*i+1][0], av[2*i+1][1]);
                wv.w = pk2(av[2*i+1][2], av[2*i+1][3]);
                const int idx = (ahalf * 32 + i * 8) ^ aswz;
                *reinterpret_cast<uint4*>(&rowp[idx]) = wv;
            }
        }
        // ---- transpose-convert & write B: 4x ds_write_b128, slot gk^swz ----
        {
#pragma unroll
            for (int j = 0; j < 4; ++j) {
                const int row = gn * 4 + j;
                uint4 wv;
                wv.x = pk2(bv[0][j], bv[1][j]);
                wv.y = pk2(bv[2][j], bv[3][j]);
                wv.z = pk2(bv[4][j], bv[5][j]);
                wv.w = pk2(bv[6][j], bv[7][j]);
                const int idx = (gk * 8) ^ (((row >> 1) & 7) << 3);
                *reinterpret_cast<uint4*>(&Bs[row * BK + idx]) = wv;
            }
        }
        __syncthreads();

        // ---- prefetch next K-tile into regs (in flight under MFMA below) ----
        if (ks + 1 < NK) {
            const float* ap = aptr0 + (ks + 1) * BK;
            const float* bp = bptr0 + (size_t)(ks + 1) * BK * DOUT;
#pragma unroll
            for (int i = 0; i < 8; ++i)
                av[i] = *reinterpret_cast<const f32x4*>(ap + i * 4);
#pragma unroll
            for (int i = 0; i < 8; ++i)
                bv[i] = *reinterpret_cast<const f32x4*>(bp + (size_t)i * DOUT);
        }

        // ---- compute: 2 k-slices x 16 MFMA ----
#pragma unroll
        for (int s = 0; s < 2; ++s) {
            short8 af[4], bfr[4];
#pragma unroll
            for (int mi = 0; mi < 4; ++mi) {
                const int row = wr * 64 + mi * 16 + lrow;
                af[mi] = *reinterpret_cast<const short8*>(
                    &As[row * BK + ((s * 32 + lkb * 8) ^ lswz)]);
            }
#pragma unroll
            for (int ni = 0; ni < 4; ++ni) {
                const int row = wc * 64 + ni * 16 + lrow;
                bfr[ni] = *reinterpret_cast<const short8*>(
                    &Bs[row * BK + ((s * 32 + lkb * 8) ^ lswz)]);
            }
#pragma unroll
            for (int mi = 0; mi < 4; ++mi)
#pragma unroll
                for (int ni = 0; ni < 4; ++ni)
                    acc[mi][ni] = __builtin_amdgcn_mfma_f32_16x16x32_bf16(
                        af[mi], bfr[ni], acc[mi][ni], 0, 0, 0);
        }
    }

    // ---- epilogue: + bias, fp32 store ----
    const float* bb = bias + (size_t)layer * DOUT + bn0;
    float* ob = out + (size_t)bm0 * (NL * DOUT) + (size_t)layer * DOUT + bn0;
#pragma unroll
    for (int mi = 0; mi < 4; ++mi) {
#pragma unroll
        for (int ni = 0; ni < 4; ++ni) {
            const int col = wc * 64 + ni * 16 + lrow;
            const float bval = bb[col];
#pragma unroll
            for (int r = 0; r < 4; ++r) {
                const int row = wr * 64 + mi * 16 + lkb * 4 + r;
                ob[(size_t)row * (NL * DOUT) + col] = acc[mi][ni][r] + bval;
            }
        }
    }
}

extern "C" void kernel_launch(void* const* d_in, const int* in_sizes, int n_in,
                              void* d_out, int out_size, void* d_ws, size_t ws_size,
                              hipStream_t stream) {
    const float* x  = (const float*)d_in[0];
    const float* w  = (const float*)d_in[1];
    const float* b  = (const float*)d_in[2];
    float* out      = (float*)d_out;

    dim3 grid(NL * (BATCH / BM) * (DOUT / BN));   // 2048
    dim3 block(256);
    hipLaunchKernelGGL(nlinear_kernel, grid, block, 0, stream, x, w, b, out);
}

// Round 4
// 119.480 us; speedup vs baseline: 1.3025x; 1.3025x over previous
//
#include <hip/hip_runtime.h>
#include <hip/hip_bf16.h>

#define NL    64
#define DIN   512
#define DOUT  512
#define BATCH 1024

#define BM 128
#define BN 128
#define BK 64
#define NK (DIN / BK)   // 8

typedef short short8 __attribute__((ext_vector_type(8)));
typedef float f32x4  __attribute__((ext_vector_type(4)));

__device__ __forceinline__ unsigned int pk2(float a, float b) {
    // lowers to v_cvt_pk_bf16_f32 (RNE)
    __hip_bfloat162 h = __float22bfloat162_rn(make_float2(a, b));
    unsigned int r;
    __builtin_memcpy(&r, &h, 4);
    return r;
}

__global__ __launch_bounds__(256) void nlinear_kernel(
        const float* __restrict__ x, const float* __restrict__ w,
        const float* __restrict__ bias, float* __restrict__ out) {
    // bf16 tiles, linear 128B rows, XOR-swizzled 16B slots: slot ^= (row>>1)&7
    __shared__ unsigned short As[BM * BK];   // 16 KB  [m][k]
    __shared__ unsigned short Bs[BN * BK];   // 16 KB  [n][k] (transposed at stage)

    const int tid = threadIdx.x;

    // XCD swizzle: 2048 blocks = 8 XCDs x 256; each XCD owns 8 whole layers
    const int bid   = blockIdx.x;
    const int nb    = (bid & 7) * 256 + (bid >> 3);
    const int layer = nb >> 5;
    const int tile  = nb & 31;
    const int bm0   = (tile >> 2) * BM;
    const int bn0   = (tile & 3) * BN;

    const int wid  = tid >> 6;
    const int lane = tid & 63;
    const int wr   = wid >> 1, wc = wid & 1;   // 2x2 waves, 64x64 each
    const int lrow = lane & 15;
    const int lkb  = lane >> 4;
    const int lswz = ((lrow >> 1) & 7) << 3;   // frag-read swizzle, ushort units

    // A staging: 8 threads/row-visit, 4 row-visits; per instr a wave covers
    // 8 rows x 128B contiguous (coalesced)
    const int arow8 = tid >> 3;          // 0..31
    const int alane = tid & 7;
    const int aswz  = (arow8 >> 1) & 7;  // same for all 4 row-visits (32j keeps (r>>1)&7)
    // B staging: thread owns 4 n-cols x 8 k-rows (4x8 transpose block)
    const int gn = tid & 31;
    const int gk = tid >> 5;

    const size_t XS = (size_t)NL * DIN;   // x row stride (floats)
    const float* xb = x + (size_t)bm0 * XS + (size_t)layer * DIN;
    const float* wb = w + (size_t)layer * DIN * DOUT + bn0;
    const float* aptr0 = xb + (size_t)arow8 * XS + alane * 8;
    const float* bptr0 = wb + (size_t)(gk * 8) * DOUT + gn * 4;

    f32x4 acc[4][4];
#pragma unroll
    for (int i = 0; i < 4; ++i)
#pragma unroll
        for (int j = 0; j < 4; ++j) acc[i][j] = (f32x4){0.f, 0.f, 0.f, 0.f};

    f32x4 av[8], bv[8];
    // prologue: tile 0 into regs
#pragma unroll
    for (int j = 0; j < 4; ++j) {
        const float* p = aptr0 + (size_t)(32 * j) * XS;
        av[2 * j]     = *reinterpret_cast<const f32x4*>(p);
        av[2 * j + 1] = *reinterpret_cast<const f32x4*>(p + 4);
    }
#pragma unroll
    for (int i = 0; i < 8; ++i)
        bv[i] = *reinterpret_cast<const f32x4*>(bptr0 + (size_t)i * DOUT);

#pragma unroll 1
    for (int ks = 0; ks < NK; ++ks) {
        // ---- convert & write A: 4x ds_write_b128 (compiler auto-waits vmcnt) ----
#pragma unroll
        for (int j = 0; j < 4; ++j) {
            uint4 wv;
            wv.x = pk2(av[2*j][0],   av[2*j][1]);
            wv.y = pk2(av[2*j][2],   av[2*j][3]);
            wv.z = pk2(av[2*j+1][0], av[2*j+1][1]);
            wv.w = pk2(av[2*j+1][2], av[2*j+1][3]);
            const int row = arow8 + 32 * j;
            const int idx = (alane ^ aswz) << 3;
            *reinterpret_cast<uint4*>(&As[row * BK + idx]) = wv;
        }
        // ---- transpose-convert & write B: 4x ds_write_b128 ----
#pragma unroll
        for (int j = 0; j < 4; ++j) {
            const int row = gn * 4 + j;
            uint4 wv;
            wv.x = pk2(bv[0][j], bv[1][j]);
            wv.y = pk2(bv[2][j], bv[3][j]);
            wv.z = pk2(bv[4][j], bv[5][j]);
            wv.w = pk2(bv[6][j], bv[7][j]);
            const int idx = (gk ^ ((row >> 1) & 7)) << 3;
            *reinterpret_cast<uint4*>(&Bs[row * BK + idx]) = wv;
        }

        // ---- issue next K-tile loads (stay in flight across BOTH barriers) ----
        if (ks + 1 < NK) {
            const float* ap = aptr0 + (ks + 1) * BK;
            const float* bp = bptr0 + (size_t)(ks + 1) * BK * DOUT;
#pragma unroll
            for (int j = 0; j < 4; ++j) {
                const float* p = ap + (size_t)(32 * j) * XS;
                av[2 * j]     = *reinterpret_cast<const f32x4*>(p);
                av[2 * j + 1] = *reinterpret_cast<const f32x4*>(p + 4);
            }
#pragma unroll
            for (int i = 0; i < 8; ++i)
                bv[i] = *reinterpret_cast<const f32x4*>(bp + (size_t)i * DOUT);
        }

        // ---- barrier WITHOUT vmcnt drain: LDS writes visible, loads keep flying ----
        asm volatile("s_waitcnt lgkmcnt(0)" ::: "memory");
        __builtin_amdgcn_sched_barrier(0);
        __builtin_amdgcn_s_barrier();
        __builtin_amdgcn_sched_barrier(0);

        // ---- compute: 2 k-slices x 16 MFMA ----
#pragma unroll
        for (int s = 0; s < 2; ++s) {
            short8 af[4], bfr[4];
#pragma unroll
            for (int mi = 0; mi < 4; ++mi) {
                const int row = wr * 64 + mi * 16 + lrow;
                af[mi] = *reinterpret_cast<const short8*>(
                    &As[row * BK + ((s * 32 + lkb * 8) ^ lswz)]);
            }
#pragma unroll
            for (int ni = 0; ni < 4; ++ni) {
                const int row = wc * 64 + ni * 16 + lrow;
                bfr[ni] = *reinterpret_cast<const short8*>(
                    &Bs[row * BK + ((s * 32 + lkb * 8) ^ lswz)]);
            }
            __builtin_amdgcn_s_setprio(1);
#pragma unroll
            for (int mi = 0; mi < 4; ++mi)
#pragma unroll
                for (int ni = 0; ni < 4; ++ni)
                    acc[mi][ni] = __builtin_amdgcn_mfma_f32_16x16x32_bf16(
                        af[mi], bfr[ni], acc[mi][ni], 0, 0, 0);
            __builtin_amdgcn_s_setprio(0);
        }

        // ---- barrier WITHOUT vmcnt drain: LDS reads done before next writes ----
        asm volatile("s_waitcnt lgkmcnt(0)" ::: "memory");
        __builtin_amdgcn_sched_barrier(0);
        __builtin_amdgcn_s_barrier();
        __builtin_amdgcn_sched_barrier(0);
    }

    // ---- epilogue: + bias, fp32 store ----
    const float* bb = bias + (size_t)layer * DOUT + bn0;
    float* ob = out + (size_t)bm0 * (NL * DOUT) + (size_t)layer * DOUT + bn0;
#pragma unroll
    for (int mi = 0; mi < 4; ++mi) {
#pragma unroll
        for (int ni = 0; ni < 4; ++ni) {
            const int col = wc * 64 + ni * 16 + lrow;
            const float bval = bb[col];
#pragma unroll
            for (int r = 0; r < 4; ++r) {
                const int row = wr * 64 + mi * 16 + lkb * 4 + r;
                ob[(size_t)row * (NL * DOUT) + col] = acc[mi][ni][r] + bval;
            }
        }
    }
}

extern "C" void kernel_launch(void* const* d_in, const int* in_sizes, int n_in,
                              void* d_out, int out_size, void* d_ws, size_t ws_size,
                              hipStream_t stream) {
    const float* x  = (const float*)d_in[0];
    const float* w  = (const float*)d_in[1];
    const float* b  = (const float*)d_in[2];
    float* out      = (float*)d_out;

    dim3 grid(NL * (BATCH / BM) * (DOUT / BN));   // 2048
    dim3 block(256);
    hipLaunchKernelGGL(nlinear_kernel, grid, block, 0, stream, x, w, b, out);
}